// Round 13
// baseline (390.315 us; speedup 1.0000x reference)
//
#include <hip/hip_runtime.h>

typedef __bf16 bf16x8 __attribute__((ext_vector_type(8)));
typedef float f32x4 __attribute__((ext_vector_type(4)));

#define NEG_SLOPE 0.01f
#define BN_EPS 1e-5f

static __device__ __forceinline__ unsigned short f2bf(float f) {
    unsigned u = __builtin_bit_cast(unsigned, f);
    unsigned r = (u + 0x7fffu + ((u >> 16) & 1u)) >> 16;
    return (unsigned short)r;
}
static __device__ __forceinline__ float lrelu(float v) {
    return fmaxf(v, 0.f) + NEG_SLOPE * fminf(v, 0.f);
}
static __device__ __forceinline__ f32x4 bn4(f32x4 v, f32x4 sc, f32x4 sh) {
    f32x4 r = v * sc + sh;
    r.x = lrelu(r.x); r.y = lrelu(r.y); r.z = lrelu(r.z); r.w = lrelu(r.w);
    return r;
}

// ---- prep: W swizzle to fragment order + dst histogram + zero stats/cnt ----
// wbs[i][os][h][l][8] (shorts): lane l of o-slice os reads a CONTIGUOUS 16B
// A-frag: o = 16*os + (l&15), d = h*32 + 8*(l>>4) + k.
__global__ __launch_bounds__(256) void prep(const float* __restrict__ We0,
                                            const float* __restrict__ We1,
                                            unsigned short* __restrict__ wbs0,
                                            unsigned short* __restrict__ wbs1,
                                            float* __restrict__ stats,
                                            int* __restrict__ counters,
                                            const int* __restrict__ dst,
                                            int* __restrict__ hist, int E) {
    const int idx = blockIdx.x * 256 + threadIdx.x;
    if (blockIdx.x == 0) {
        stats[threadIdx.x] = 0.f;                  // stats[0..255]
        if (threadIdx.x < 2) counters[threadIdx.x] = 0;
    }
    if (idx < 65536) {
        const int t = idx;                         // 0..65535
        const float* We = (t >> 15) ? We1 : We0;
        unsigned short* wbs = (t >> 15) ? wbs1 : wbs0;
        const int r = t & 32767;                   // [i:6][os:2][h:1][l:6]
        const int i = r >> 9, os = (r >> 7) & 3, h = (r >> 6) & 1, l = r & 63;
        const float* sp = We + (size_t)(i * 64 + 16 * os + (l & 15)) * 64
                             + h * 32 + 8 * (l >> 4);
        const f32x4 v0 = *reinterpret_cast<const f32x4*>(sp);
        const f32x4 v1 = *reinterpret_cast<const f32x4*>(sp + 4);
        ushort4 u0, u1;
        u0.x = f2bf(v0.x); u0.y = f2bf(v0.y); u0.z = f2bf(v0.z); u0.w = f2bf(v0.w);
        u1.x = f2bf(v1.x); u1.y = f2bf(v1.y); u1.z = f2bf(v1.z); u1.w = f2bf(v1.w);
        *reinterpret_cast<ushort4*>(wbs + (size_t)r * 8) = u0;
        *reinterpret_cast<ushort4*>(wbs + (size_t)r * 8 + 4) = u1;
    } else {
        const int e = idx - 65536;                 // 0..E-1
        if (e < E) atomicAdd(&hist[dst[e]], 1);
    }
}

// ---- exclusive prefix sum over hist[0..N) -> ofs[0..N], cur copy (1 block) ----
__global__ __launch_bounds__(256) void scan_kernel(const int* __restrict__ hist,
                                                   int* __restrict__ ofs,
                                                   int* __restrict__ cur, int N) {
    __shared__ int psum[256];
    const int tid = threadIdx.x;
    const int per = N / 256;                       // 32
    const int base = tid * per;
    int loc[32];
    int s = 0;
#pragma unroll
    for (int k = 0; k < 32; ++k) { loc[k] = s; s += hist[base + k]; }
    psum[tid] = s;
    __syncthreads();
    if (tid == 0) {
        int a = 0;
        for (int i = 0; i < 256; ++i) { int t = psum[i]; psum[i] = a; a += t; }
        ofs[N] = a;
    }
    __syncthreads();
    const int off = psum[tid];
#pragma unroll
    for (int k = 0; k < 32; ++k) {
        ofs[base + k] = off + loc[k];
        cur[base + k] = off + loc[k];
    }
}

// ---- compute CSR slot for each edge ----
__global__ __launch_bounds__(256) void scatter_kernel(const int* __restrict__ dst,
                                                      int* __restrict__ cur,
                                                      int* __restrict__ perm) {
    const int e = blockIdx.x * 256 + threadIdx.x;
    perm[e] = atomicAdd(&cur[dst[e]], 1);
}

// ---- reorder edges into CSR order: ef (bf16) rows + src ids ----
__global__ __launch_bounds__(256) void reorder_ef(const float* __restrict__ ef,
                                                  const int* __restrict__ perm,
                                                  const int* __restrict__ src,
                                                  unsigned short* __restrict__ ef_bs,
                                                  int* __restrict__ src_s) {
    const int idx = blockIdx.x * 256 + threadIdx.x;   // 0 .. E*16-1
    const int e = idx >> 4, c = idx & 15;
    const int p = perm[e];
    const f32x4 v = *reinterpret_cast<const f32x4*>(ef + (size_t)e * 64 + c * 4);
    ushort4 u;
    u.x = f2bf(v.x); u.y = f2bf(v.y); u.z = f2bf(v.z); u.w = f2bf(v.w);
    *reinterpret_cast<ushort4*>(ef_bs + (size_t)p * 64 + c * 4) = u;
    if (c == 0) src_s[p] = src[e];
}

// ---- root + node-bias matmuls; optional BN(x) on load ----
// y=0: aggr = BN(x)@Wr + br ; y=1: NB = BN(x)@be
__global__ __launch_bounds__(256) void node_mm2(const float* __restrict__ x,
                                                const float* __restrict__ Wr,
                                                const float* __restrict__ br,
                                                float* __restrict__ aggr,
                                                const float* __restrict__ be,
                                                float* __restrict__ NB,
                                                const float* __restrict__ ss) {
    const float* M; const float* bias; float* out;
    if (blockIdx.y == 0) { M = Wr; bias = br; out = aggr; }
    else                 { M = be; bias = nullptr; out = NB; }
    __shared__ float Ml[64][64];
    __shared__ float xl[64][64];
    const int tid = threadIdx.x;
    const int n0 = blockIdx.x * 64;
    for (int f = tid; f < 1024; f += 256) {
        int r = f >> 4, c = f & 15;
        *reinterpret_cast<float4*>(&Ml[r][c * 4]) =
            *reinterpret_cast<const float4*>(M + (size_t)r * 64 + c * 4);
        f32x4 xv = *reinterpret_cast<const f32x4*>(x + (size_t)(n0 + r) * 64 + c * 4);
        if (ss) {
            const f32x4 sc = *reinterpret_cast<const f32x4*>(ss + c * 4);
            const f32x4 sh = *reinterpret_cast<const f32x4*>(ss + 64 + c * 4);
            xv = bn4(xv, sc, sh);
        }
        *reinterpret_cast<f32x4*>(&xl[r][c * 4]) = xv;
    }
    __syncthreads();
    const int o = tid & 63, g = tid >> 6;
    float acc[16] = {};
    for (int i4 = 0; i4 < 16; ++i4) {
        float m0 = Ml[4 * i4 + 0][o], m1 = Ml[4 * i4 + 1][o];
        float m2 = Ml[4 * i4 + 2][o], m3 = Ml[4 * i4 + 3][o];
#pragma unroll
        for (int k = 0; k < 16; ++k) {
            const f32x4 xv = *reinterpret_cast<const f32x4*>(&xl[g + 4 * k][4 * i4]);
            acc[k] += xv.x * m0 + xv.y * m1 + xv.z * m2 + xv.w * m3;
        }
    }
    const float b = bias ? bias[o] : 0.f;
#pragma unroll
    for (int k = 0; k < 16; ++k)
        out[(size_t)(n0 + g + 4 * k) * 64 + o] = acc[k] + b;
}

// ---- fused NNConv message: 128 edges/block, 512 thr / 8 waves.
// Wave w: edge-half eh=w>>2 (edges 64*eh..+63), o-slice os=w&3.
// T14 register staging of W chunks; edges already CSR-sorted -> linear stores.
__global__ __launch_bounds__(512, 2) void msg_fused(
    const unsigned short* __restrict__ ef_bs,  // [E][64] bf16, CSR order
    const unsigned short* __restrict__ wbs,    // fragment-order [i][os][h][l][8]
    const float* __restrict__ x,               // [N][64] f32 (pre-BN if ss)
    const float* __restrict__ NB,              // [N][64] f32
    const int* __restrict__ src_s,             // [E] src ids, CSR order
    float* __restrict__ msg,                   // [E][64] f32 out, CSR order
    const float* __restrict__ ss) {            // BN scale/shift for x, or null
    __shared__ unsigned short wlds[16384];     // 32KB: one chunk = 4 i
    __shared__ float xT2[8192];                // 32KB: [i][ln][ehh] = [i*128+ln*8+ehh]
    const int tid = threadIdx.x;
    const int e0 = blockIdx.x * 128;

    // gather x rows of the 128 src nodes -> xT2 (f32, BN on load)
#pragma unroll
    for (int it = 0; it < 4; ++it) {
        int f = it * 512 + tid;                // 0..2047
        int e = f & 127, c = f >> 7;           // c in 0..15
        int s = src_s[e0 + e];
        f32x4 xv = *reinterpret_cast<const f32x4*>(x + (size_t)s * 64 + c * 4);
        if (ss) {
            const f32x4 sc = *reinterpret_cast<const f32x4*>(ss + c * 4);
            const f32x4 sh = *reinterpret_cast<const f32x4*>(ss + 64 + c * 4);
            xv = bn4(xv, sc, sh);
        }
        const int eln = e & 15, ehh = e >> 4;  // ehh in 0..7
        xT2[(4 * c + 0) * 128 + eln * 8 + ehh] = xv.x;
        xT2[(4 * c + 1) * 128 + eln * 8 + ehh] = xv.y;
        xT2[(4 * c + 2) * 128 + eln * 8 + ehh] = xv.z;
        xT2[(4 * c + 3) * 128 + eln * 8 + ehh] = xv.w;
    }

    const int w = tid >> 6, l = tid & 63, lg = l >> 4, ln = l & 15;
    const int os = w & 3, eh = w >> 2;

    // ef B-frags: this wave's 4 edge tiles (of its 64-edge half)
    bf16x8 B0[4], B1[4];
#pragma unroll
    for (int tt = 0; tt < 4; ++tt) {
        const unsigned short* pe = ef_bs + (size_t)(e0 + 64 * eh + 16 * tt + ln) * 64 + 8 * lg;
        B0[tt] = *reinterpret_cast<const bf16x8*>(pe);
        B1[tt] = *reinterpret_cast<const bf16x8*>(pe + 32);
    }

    // T14 register staging of W chunks (32KB each; 512 thr x 4 x 16B)
    const char* gW = (const char*)wbs;
    char* wldsB = (char*)wlds;
#define GLD(c, j) (*reinterpret_cast<const bf16x8*>(gW + (size_t)(c) * 32768 + (j) * 8192 + tid * 16))
#define SST(j, v) (*reinterpret_cast<bf16x8*>(wldsB + (j) * 8192 + tid * 16) = (v))

    bf16x8 S0 = GLD(0, 0), S1 = GLD(0, 1), S2 = GLD(0, 2), S3 = GLD(0, 3);
    SST(0, S0); SST(1, S1); SST(2, S2); SST(3, S3);
    S0 = GLD(1, 0); S1 = GLD(1, 1); S2 = GLD(1, 2); S3 = GLD(1, 3);
    __syncthreads();   // xT2 + chunk-0 visible

    f32x4 acc[4] = {};
    const unsigned short* wb_ = wlds + os * 1024 + l * 8;
    for (int t = 0; t < 16; ++t) {
#pragma unroll
        for (int ii = 0; ii < 4; ++ii) {
            const bf16x8 A0 = *reinterpret_cast<const bf16x8*>(wb_ + ii * 4096);
            const bf16x8 A1 = *reinterpret_cast<const bf16x8*>(wb_ + ii * 4096 + 512);
            const f32x4 xs = *reinterpret_cast<const f32x4*>(
                &xT2[(t * 4 + ii) * 128 + ln * 8 + eh * 4]);
#pragma unroll
            for (int tt = 0; tt < 4; ++tt) {
                f32x4 c = {};
                c = __builtin_amdgcn_mfma_f32_16x16x32_bf16(A0, B0[tt], c, 0, 0, 0);
                c = __builtin_amdgcn_mfma_f32_16x16x32_bf16(A1, B1[tt], c, 0, 0, 0);
                acc[tt] += xs[tt] * c;
            }
        }
        __syncthreads();                       // all waves done reading wlds
        if (t < 15) {
            SST(0, S0); SST(1, S1); SST(2, S2); SST(3, S3);
            if (t < 14) {
                S0 = GLD(t + 2, 0); S1 = GLD(t + 2, 1);
                S2 = GLD(t + 2, 2); S3 = GLD(t + 2, 3);
            }
            __syncthreads();                   // next chunk visible
        }
    }
#undef GLD
#undef SST

    // epilogue: add NB[src][o-slice], LINEAR store to msg (CSR order)
#pragma unroll
    for (int tt = 0; tt < 4; ++tt) {
        const int e = e0 + 64 * eh + 16 * tt + ln;
        const int s = src_s[e];
        const f32x4 nbv = *reinterpret_cast<const f32x4*>(NB + (size_t)s * 64 + os * 16 + 4 * lg);
        const f32x4 add = acc[tt] + nbv;
        *reinterpret_cast<f32x4*>(msg + (size_t)e * 64 + os * 16 + 4 * lg) = add;
    }
}

// ---- gather (contiguous CSR rows) + BN stats + last-block finalize ----
// 1 node per wave, 4 nodes/block, grid N/4.
__global__ __launch_bounds__(256) void gather_bn(
    const float* __restrict__ msg,     // [E][64] CSR order
    const int* __restrict__ ofs,       // [N+1]
    float* __restrict__ aggr,          // [N][64] in: root term; out: h
    const float* __restrict__ gamma,
    const float* __restrict__ beta,
    float* __restrict__ sums,          // [128]
    float* __restrict__ ss,            // [128] out
    float invN, int* __restrict__ counter, int nblk) {
    const int tid = threadIdx.x;
    const int w = tid >> 6, lane = tid & 63;
    const int v = blockIdx.x * 4 + w;
    const int beg = ofs[v], end = ofs[v + 1];
    float a0 = 0.f, a1 = 0.f;
    int j = beg;
    for (; j + 2 <= end; j += 2) {
        a0 += msg[(size_t)(j + 0) * 64 + lane];
        a1 += msg[(size_t)(j + 1) * 64 + lane];
    }
    if (j < end) a0 += msg[(size_t)j * 64 + lane];
    const float val = aggr[(size_t)v * 64 + lane] + a0 + a1;
    aggr[(size_t)v * 64 + lane] = val;

    __shared__ float red[2][4][64];
    __shared__ int lastFlag;
    red[0][w][lane] = val; red[1][w][lane] = val * val;
    __syncthreads();
    if (w == 0) {
        float s  = red[0][0][lane] + red[0][1][lane] + red[0][2][lane] + red[0][3][lane];
        float s2 = red[1][0][lane] + red[1][1][lane] + red[1][2][lane] + red[1][3][lane];
        atomicAdd(&sums[lane], s);
        atomicAdd(&sums[64 + lane], s2);
    }
    __threadfence();
    __syncthreads();
    if (tid == 0) lastFlag = (atomicAdd(counter, 1) == nblk - 1);
    __syncthreads();
    if (lastFlag && tid < 64) {
        const float sv  = atomicAdd(&sums[tid], 0.f);        // coherent read
        const float sv2 = atomicAdd(&sums[64 + tid], 0.f);
        const float mean = sv * invN;
        const float var  = sv2 * invN - mean * mean;
        const float sc = gamma[tid] * rsqrtf(var + BN_EPS);
        ss[tid] = sc;
        ss[64 + tid] = beta[tid] - mean * sc;
    }
}

// ---- final: out[n,q] = sum_o BN(x)[n,o]*W_lin[q,o] + b_lin[q] ----
__global__ __launch_bounds__(256) void out_kernel(const float* __restrict__ x2,
                                                  const float* __restrict__ Wl,
                                                  const float* __restrict__ bl,
                                                  float* __restrict__ out,
                                                  const float* __restrict__ ss) {
    __shared__ float Wt[64][129];
    __shared__ float xl[64][64];
    const int tid = threadIdx.x;
    const int n0 = blockIdx.x * 64;
    for (int f = tid; f < 8192; f += 256) {
        int q = f >> 6, o = f & 63;
        Wt[o][q] = Wl[f];
    }
    for (int f = tid; f < 1024; f += 256) {
        int r = f >> 4, c = f & 15;
        f32x4 xv = *reinterpret_cast<const f32x4*>(x2 + (size_t)(n0 + r) * 64 + c * 4);
        const f32x4 sc = *reinterpret_cast<const f32x4*>(ss + c * 4);
        const f32x4 sh = *reinterpret_cast<const f32x4*>(ss + 64 + c * 4);
        xv = bn4(xv, sc, sh);
        *reinterpret_cast<f32x4*>(&xl[r][c * 4]) = xv;
    }
    __syncthreads();
    const int q = tid & 127, ng = tid >> 7;
    float acc[32] = {};
    for (int o4 = 0; o4 < 16; ++o4) {
        float w0 = Wt[4 * o4 + 0][q], w1 = Wt[4 * o4 + 1][q];
        float w2 = Wt[4 * o4 + 2][q], w3 = Wt[4 * o4 + 3][q];
#pragma unroll
        for (int k = 0; k < 32; ++k) {
            const f32x4 xv = *reinterpret_cast<const f32x4*>(&xl[ng + 2 * k][4 * o4]);
            acc[k] += xv.x * w0 + xv.y * w1 + xv.z * w2 + xv.w * w3;
        }
    }
    const float b = bl[q];
#pragma unroll
    for (int k = 0; k < 32; ++k)
        out[(size_t)(n0 + ng + 2 * k) * 128 + q] = acc[k] + b;
}

extern "C" void kernel_launch(void* const* d_in, const int* in_sizes, int n_in,
                              void* d_out, int out_size, void* d_ws, size_t ws_size,
                              hipStream_t stream) {
    const float* nf      = (const float*)d_in[0];
    const int*   ei      = (const int*)d_in[1];
    const float* ef      = (const float*)d_in[2];
    const float* W_edge0 = (const float*)d_in[4];
    const float* b_edge0 = (const float*)d_in[5];
    const float* W_root0 = (const float*)d_in[6];
    const float* b_root0 = (const float*)d_in[7];
    const float* gamma0  = (const float*)d_in[8];
    const float* beta0   = (const float*)d_in[9];
    const float* W_edge1 = (const float*)d_in[10];
    const float* b_edge1 = (const float*)d_in[11];
    const float* W_root1 = (const float*)d_in[12];
    const float* b_root1 = (const float*)d_in[13];
    const float* gamma1  = (const float*)d_in[14];
    const float* beta1   = (const float*)d_in[15];
    const float* W_lin   = (const float*)d_in[16];
    const float* b_lin   = (const float*)d_in[17];

    const int N = in_sizes[0] / 64;   // 8192
    const int E = in_sizes[1] / 2;    // 32768
    const int* src = ei;
    const int* dst = ei + E;

    unsigned short* ef_bs = (unsigned short*)d_ws;         // E*64 shorts (CSR)
    unsigned short* wbs0  = ef_bs + (size_t)E * 64;        // 262144
    unsigned short* wbs1  = wbs0 + 262144;                 // 262144
    float* msg   = (float*)(wbs1 + 262144);                // E*64 f32 (CSR)
    float* aggr0 = msg + (size_t)E * 64;                   // N*64
    float* aggr1 = aggr0 + (size_t)N * 64;                 // N*64
    float* NBbuf = aggr1 + (size_t)N * 64;                 // N*64
    float* stats = NBbuf + (size_t)N * 64;                 // 256
    float* ssbuf = stats + 256;                            // 256
    int*   cnt   = (int*)(ssbuf + 256);                    // 2
    int*   hist  = cnt + 2;                                // N
    int*   ofs   = hist + N;                               // N+1
    int*   cur   = ofs + N + 1;                            // N
    int*   perm  = cur + N;                                // E
    int*   src_s = perm + E;                               // E

    const float invN = 1.0f / (float)N;

    hipMemsetAsync(hist, 0, N * sizeof(int), stream);
    prep<<<(65536 + E) / 256, 256, 0, stream>>>(W_edge0, W_edge1, wbs0, wbs1,
                                                stats, cnt, dst, hist, E);
    scan_kernel<<<1, 256, 0, stream>>>(hist, ofs, cur, N);
    scatter_kernel<<<E / 256, 256, 0, stream>>>(dst, cur, perm);
    reorder_ef<<<E * 16 / 256, 256, 0, stream>>>(ef, perm, src, ef_bs, src_s);

    // ---- layer 0 ----
    node_mm2<<<dim3(N / 64, 2), 256, 0, stream>>>(nf, W_root0, b_root0, aggr0,
                                                  b_edge0, NBbuf, nullptr);
    msg_fused<<<E / 128, 512, 0, stream>>>(ef_bs, wbs0, nf, NBbuf, src_s, msg, nullptr);
    gather_bn<<<N / 4, 256, 0, stream>>>(msg, ofs, aggr0, gamma0, beta0,
                                         stats, ssbuf, invN, cnt + 0, N / 4);

    // ---- layer 1 (x1 = BN(aggr0) applied on load everywhere) ----
    node_mm2<<<dim3(N / 64, 2), 256, 0, stream>>>(aggr0, W_root1, b_root1, aggr1,
                                                  b_edge1, NBbuf, ssbuf);
    msg_fused<<<E / 128, 512, 0, stream>>>(ef_bs, wbs1, aggr0, NBbuf, src_s, msg, ssbuf);
    gather_bn<<<N / 4, 256, 0, stream>>>(msg, ofs, aggr1, gamma1, beta1,
                                         stats + 128, ssbuf + 128, invN, cnt + 1, N / 4);

    // ---- final linear (x2 = BN(aggr1) on load) ----
    out_kernel<<<N / 64, 256, 0, stream>>>(aggr1, W_lin, b_lin, (float*)d_out, ssbuf + 128);
}

// Round 14
// 143.776 us; speedup vs baseline: 2.7147x; 2.7147x over previous
//
#include <hip/hip_runtime.h>

typedef __bf16 bf16x8 __attribute__((ext_vector_type(8)));
typedef float f32x4 __attribute__((ext_vector_type(4)));

#define NEG_SLOPE 0.01f
#define BN_EPS 1e-5f

static __device__ __forceinline__ unsigned short f2bf(float f) {
    unsigned u = __builtin_bit_cast(unsigned, f);
    unsigned r = (u + 0x7fffu + ((u >> 16) & 1u)) >> 16;
    return (unsigned short)r;
}
static __device__ __forceinline__ float lrelu(float v) {
    return fmaxf(v, 0.f) + NEG_SLOPE * fminf(v, 0.f);
}
static __device__ __forceinline__ f32x4 bn4(f32x4 v, f32x4 sc, f32x4 sh) {
    f32x4 r = v * sc + sh;
    r.x = lrelu(r.x); r.y = lrelu(r.y); r.z = lrelu(r.z); r.w = lrelu(r.w);
    return r;
}

// ---- prep: W swizzle to fragment order + dst histogram + zero stats/cnt ----
// wbs[i][os][h][l][8] (shorts): lane l of o-slice os reads a CONTIGUOUS 16B
// A-frag: o = 16*os + (l&15), d = h*32 + 8*(l>>4) + k.
__global__ __launch_bounds__(256) void prep(const float* __restrict__ We0,
                                            const float* __restrict__ We1,
                                            unsigned short* __restrict__ wbs0,
                                            unsigned short* __restrict__ wbs1,
                                            float* __restrict__ stats,
                                            int* __restrict__ counters,
                                            const int* __restrict__ dst,
                                            int* __restrict__ hist, int E) {
    const int idx = blockIdx.x * 256 + threadIdx.x;
    if (blockIdx.x == 0) {
        stats[threadIdx.x] = 0.f;                  // stats[0..255]
        if (threadIdx.x < 2) counters[threadIdx.x] = 0;
    }
    if (idx < 65536) {
        const int t = idx;                         // 0..65535
        const float* We = (t >> 15) ? We1 : We0;
        unsigned short* wbs = (t >> 15) ? wbs1 : wbs0;
        const int r = t & 32767;                   // [i:6][os:2][h:1][l:6]
        const int i = r >> 9, os = (r >> 7) & 3, h = (r >> 6) & 1, l = r & 63;
        const float* sp = We + (size_t)(i * 64 + 16 * os + (l & 15)) * 64
                             + h * 32 + 8 * (l >> 4);
        const f32x4 v0 = *reinterpret_cast<const f32x4*>(sp);
        const f32x4 v1 = *reinterpret_cast<const f32x4*>(sp + 4);
        ushort4 u0, u1;
        u0.x = f2bf(v0.x); u0.y = f2bf(v0.y); u0.z = f2bf(v0.z); u0.w = f2bf(v0.w);
        u1.x = f2bf(v1.x); u1.y = f2bf(v1.y); u1.z = f2bf(v1.z); u1.w = f2bf(v1.w);
        *reinterpret_cast<ushort4*>(wbs + (size_t)r * 8) = u0;
        *reinterpret_cast<ushort4*>(wbs + (size_t)r * 8 + 4) = u1;
    } else {
        const int e = idx - 65536;                 // 0..E-1
        if (e < E) atomicAdd(&hist[dst[e]], 1);
    }
}

// ---- exclusive prefix sum over hist[0..N) -> ofs[0..N], cur copy (1 block) ----
__global__ __launch_bounds__(256) void scan_kernel(const int* __restrict__ hist,
                                                   int* __restrict__ ofs,
                                                   int* __restrict__ cur, int N) {
    __shared__ int wsum[4];
    const int tid = threadIdx.x;
    const int per = N / 256;                       // 32
    const int base = tid * per;
    int loc[32];
    int s = 0;
#pragma unroll
    for (int k = 0; k < 32; ++k) { loc[k] = s; s += hist[base + k]; }
    // wave-level exclusive scan of per-thread sums (64 lanes, shfl)
    const int lane = tid & 63, w = tid >> 6;
    int run = s;
#pragma unroll
    for (int d = 1; d < 64; d <<= 1) {
        int up = __shfl_up(run, d, 64);
        if (lane >= d) run += up;
    }
    const int excl = run - s;                      // exclusive within wave
    if (lane == 63) wsum[w] = run;                 // wave total
    __syncthreads();
    int woff = 0;
#pragma unroll
    for (int i = 0; i < 4; ++i) woff += (i < w) ? wsum[i] : 0;
    if (tid == 255) ofs[N] = woff + run;
    const int off = woff + excl;
#pragma unroll
    for (int k = 0; k < 32; ++k) {
        ofs[base + k] = off + loc[k];
        cur[base + k] = off + loc[k];
    }
}

// ---- compute CSR slot for each edge ----
__global__ __launch_bounds__(256) void scatter_kernel(const int* __restrict__ dst,
                                                      int* __restrict__ cur,
                                                      int* __restrict__ perm) {
    const int e = blockIdx.x * 256 + threadIdx.x;
    perm[e] = atomicAdd(&cur[dst[e]], 1);
}

// ---- reorder edges into CSR order: ef (bf16) rows + src ids ----
__global__ __launch_bounds__(256) void reorder_ef(const float* __restrict__ ef,
                                                  const int* __restrict__ perm,
                                                  const int* __restrict__ src,
                                                  unsigned short* __restrict__ ef_bs,
                                                  int* __restrict__ src_s) {
    const int idx = blockIdx.x * 256 + threadIdx.x;   // 0 .. E*16-1
    const int e = idx >> 4, c = idx & 15;
    const int p = perm[e];
    const f32x4 v = *reinterpret_cast<const f32x4*>(ef + (size_t)e * 64 + c * 4);
    ushort4 u;
    u.x = f2bf(v.x); u.y = f2bf(v.y); u.z = f2bf(v.z); u.w = f2bf(v.w);
    *reinterpret_cast<ushort4*>(ef_bs + (size_t)p * 64 + c * 4) = u;
    if (c == 0) src_s[p] = src[e];
}

// ---- root + node-bias matmuls; optional BN(x) on load ----
// y=0: aggr = BN(x)@Wr + br ; y=1: NB = BN(x)@be
__global__ __launch_bounds__(256) void node_mm2(const float* __restrict__ x,
                                                const float* __restrict__ Wr,
                                                const float* __restrict__ br,
                                                float* __restrict__ aggr,
                                                const float* __restrict__ be,
                                                float* __restrict__ NB,
                                                const float* __restrict__ ss) {
    const float* M; const float* bias; float* out;
    if (blockIdx.y == 0) { M = Wr; bias = br; out = aggr; }
    else                 { M = be; bias = nullptr; out = NB; }
    __shared__ float Ml[64][64];
    __shared__ float xl[64][64];
    const int tid = threadIdx.x;
    const int n0 = blockIdx.x * 64;
    for (int f = tid; f < 1024; f += 256) {
        int r = f >> 4, c = f & 15;
        *reinterpret_cast<float4*>(&Ml[r][c * 4]) =
            *reinterpret_cast<const float4*>(M + (size_t)r * 64 + c * 4);
        f32x4 xv = *reinterpret_cast<const f32x4*>(x + (size_t)(n0 + r) * 64 + c * 4);
        if (ss) {
            const f32x4 sc = *reinterpret_cast<const f32x4*>(ss + c * 4);
            const f32x4 sh = *reinterpret_cast<const f32x4*>(ss + 64 + c * 4);
            xv = bn4(xv, sc, sh);
        }
        *reinterpret_cast<f32x4*>(&xl[r][c * 4]) = xv;
    }
    __syncthreads();
    const int o = tid & 63, g = tid >> 6;
    float acc[16] = {};
    for (int i4 = 0; i4 < 16; ++i4) {
        float m0 = Ml[4 * i4 + 0][o], m1 = Ml[4 * i4 + 1][o];
        float m2 = Ml[4 * i4 + 2][o], m3 = Ml[4 * i4 + 3][o];
#pragma unroll
        for (int k = 0; k < 16; ++k) {
            const f32x4 xv = *reinterpret_cast<const f32x4*>(&xl[g + 4 * k][4 * i4]);
            acc[k] += xv.x * m0 + xv.y * m1 + xv.z * m2 + xv.w * m3;
        }
    }
    const float b = bias ? bias[o] : 0.f;
#pragma unroll
    for (int k = 0; k < 16; ++k)
        out[(size_t)(n0 + g + 4 * k) * 64 + o] = acc[k] + b;
}

// ---- fused NNConv message: 128 edges/block, 512 thr / 8 waves.
// Wave w: edge-half eh=w>>2 (edges 64*eh..+63), o-slice os=w&3.
// T14 register staging of W chunks; edges CSR-sorted -> linear stores.
__global__ __launch_bounds__(512, 2) void msg_fused(
    const unsigned short* __restrict__ ef_bs,  // [E][64] bf16, CSR order
    const unsigned short* __restrict__ wbs,    // fragment-order [i][os][h][l][8]
    const float* __restrict__ x,               // [N][64] f32 (pre-BN if ss)
    const float* __restrict__ NB,              // [N][64] f32
    const int* __restrict__ src_s,             // [E] src ids, CSR order
    float* __restrict__ msg,                   // [E][64] f32 out, CSR order
    const float* __restrict__ ss) {            // BN scale/shift for x, or null
    __shared__ unsigned short wlds[16384];     // 32KB: one chunk = 4 i
    __shared__ float xT2[8192];                // 32KB: [i][ln][ehh]
    const int tid = threadIdx.x;
    const int e0 = blockIdx.x * 128;

    // gather x rows of the 128 src nodes -> xT2 (f32, BN on load)
#pragma unroll
    for (int it = 0; it < 4; ++it) {
        int f = it * 512 + tid;                // 0..2047
        int e = f & 127, c = f >> 7;           // c in 0..15
        int s = src_s[e0 + e];
        f32x4 xv = *reinterpret_cast<const f32x4*>(x + (size_t)s * 64 + c * 4);
        if (ss) {
            const f32x4 sc = *reinterpret_cast<const f32x4*>(ss + c * 4);
            const f32x4 sh = *reinterpret_cast<const f32x4*>(ss + 64 + c * 4);
            xv = bn4(xv, sc, sh);
        }
        const int eln = e & 15, ehh = e >> 4;  // ehh in 0..7
        xT2[(4 * c + 0) * 128 + eln * 8 + ehh] = xv.x;
        xT2[(4 * c + 1) * 128 + eln * 8 + ehh] = xv.y;
        xT2[(4 * c + 2) * 128 + eln * 8 + ehh] = xv.z;
        xT2[(4 * c + 3) * 128 + eln * 8 + ehh] = xv.w;
    }

    const int w = tid >> 6, l = tid & 63, lg = l >> 4, ln = l & 15;
    const int os = w & 3, eh = w >> 2;

    // ef B-frags: this wave's 4 edge tiles (of its 64-edge half)
    bf16x8 B0[4], B1[4];
#pragma unroll
    for (int tt = 0; tt < 4; ++tt) {
        const unsigned short* pe = ef_bs + (size_t)(e0 + 64 * eh + 16 * tt + ln) * 64 + 8 * lg;
        B0[tt] = *reinterpret_cast<const bf16x8*>(pe);
        B1[tt] = *reinterpret_cast<const bf16x8*>(pe + 32);
    }

    // T14 register staging of W chunks (32KB each; 512 thr x 4 x 16B)
    const char* gW = (const char*)wbs;
    char* wldsB = (char*)wlds;
#define GLD(c, j) (*reinterpret_cast<const bf16x8*>(gW + (size_t)(c) * 32768 + (j) * 8192 + tid * 16))
#define SST(j, v) (*reinterpret_cast<bf16x8*>(wldsB + (j) * 8192 + tid * 16) = (v))

    bf16x8 S0 = GLD(0, 0), S1 = GLD(0, 1), S2 = GLD(0, 2), S3 = GLD(0, 3);
    SST(0, S0); SST(1, S1); SST(2, S2); SST(3, S3);
    S0 = GLD(1, 0); S1 = GLD(1, 1); S2 = GLD(1, 2); S3 = GLD(1, 3);
    __syncthreads();   // xT2 + chunk-0 visible

    f32x4 acc[4] = {};
    const unsigned short* wb_ = wlds + os * 1024 + l * 8;
    for (int t = 0; t < 16; ++t) {
#pragma unroll
        for (int ii = 0; ii < 4; ++ii) {
            const bf16x8 A0 = *reinterpret_cast<const bf16x8*>(wb_ + ii * 4096);
            const bf16x8 A1 = *reinterpret_cast<const bf16x8*>(wb_ + ii * 4096 + 512);
            const f32x4 xs = *reinterpret_cast<const f32x4*>(
                &xT2[(t * 4 + ii) * 128 + ln * 8 + eh * 4]);
#pragma unroll
            for (int tt = 0; tt < 4; ++tt) {
                f32x4 c = {};
                c = __builtin_amdgcn_mfma_f32_16x16x32_bf16(A0, B0[tt], c, 0, 0, 0);
                c = __builtin_amdgcn_mfma_f32_16x16x32_bf16(A1, B1[tt], c, 0, 0, 0);
                acc[tt] += xs[tt] * c;
            }
        }
        __syncthreads();                       // all waves done reading wlds
        if (t < 15) {
            SST(0, S0); SST(1, S1); SST(2, S2); SST(3, S3);
            if (t < 14) {
                S0 = GLD(t + 2, 0); S1 = GLD(t + 2, 1);
                S2 = GLD(t + 2, 2); S3 = GLD(t + 2, 3);
            }
            __syncthreads();                   // next chunk visible
        }
    }
#undef GLD
#undef SST

    // epilogue: add NB[src][o-slice], LINEAR store to msg (CSR order)
#pragma unroll
    for (int tt = 0; tt < 4; ++tt) {
        const int e = e0 + 64 * eh + 16 * tt + ln;
        const int s = src_s[e];
        const f32x4 nbv = *reinterpret_cast<const f32x4*>(NB + (size_t)s * 64 + os * 16 + 4 * lg);
        const f32x4 add = acc[tt] + nbv;
        *reinterpret_cast<f32x4*>(msg + (size_t)e * 64 + os * 16 + 4 * lg) = add;
    }
}

// ---- gather: node v sums its CONTIGUOUS msg rows (no fence, no stats) ----
__global__ __launch_bounds__(256) void gather_k(const float* __restrict__ msg,
                                                const int* __restrict__ ofs,
                                                float* __restrict__ aggr) {
    const int tid = threadIdx.x;
    const int w = tid >> 6, lane = tid & 63;
    const int v = blockIdx.x * 4 + w;
    const int beg = ofs[v], end = ofs[v + 1];
    float a0 = 0.f, a1 = 0.f, a2 = 0.f, a3 = 0.f;
    int j = beg;
    for (; j + 4 <= end; j += 4) {
        a0 += msg[(size_t)(j + 0) * 64 + lane];
        a1 += msg[(size_t)(j + 1) * 64 + lane];
        a2 += msg[(size_t)(j + 2) * 64 + lane];
        a3 += msg[(size_t)(j + 3) * 64 + lane];
    }
    for (; j < end; ++j) a0 += msg[(size_t)j * 64 + lane];
    aggr[(size_t)v * 64 + lane] += (a0 + a1) + (a2 + a3);
}

// ---- BN statistics + last-block finalize (64 blocks; fence is cheap here) ----
__global__ __launch_bounds__(256) void bn_stats(const float* __restrict__ h,
                                                float* __restrict__ sums,
                                                const float* __restrict__ gamma,
                                                const float* __restrict__ beta,
                                                float* __restrict__ ss,
                                                float invN,
                                                int* __restrict__ counter,
                                                int nblk) {
    const int tid = threadIdx.x;
    const int o = tid & 63, g = tid >> 6;
    const int n0 = blockIdx.x * 128;
    float s = 0.f, s2 = 0.f;
    for (int k = 0; k < 32; ++k) {
        float v = h[(size_t)(n0 + g * 32 + k) * 64 + o];
        s += v; s2 += v * v;
    }
    __shared__ float red[2][4][64];
    __shared__ int lastFlag;
    red[0][g][o] = s; red[1][g][o] = s2;
    __syncthreads();
    if (g == 0) {
        s  = red[0][0][o] + red[0][1][o] + red[0][2][o] + red[0][3][o];
        s2 = red[1][0][o] + red[1][1][o] + red[1][2][o] + red[1][3][o];
        atomicAdd(&sums[o], s);
        atomicAdd(&sums[64 + o], s2);
    }
    __threadfence();
    __syncthreads();
    if (tid == 0) lastFlag = (atomicAdd(counter, 1) == nblk - 1);
    __syncthreads();
    if (lastFlag && tid < 64) {
        const float sv  = atomicAdd(&sums[tid], 0.f);        // coherent read
        const float sv2 = atomicAdd(&sums[64 + tid], 0.f);
        const float mean = sv * invN;
        const float var  = sv2 * invN - mean * mean;
        const float sc = gamma[tid] * rsqrtf(var + BN_EPS);
        ss[tid] = sc;
        ss[64 + tid] = beta[tid] - mean * sc;
    }
}

// ---- final: out[n,q] = sum_o BN(x)[n,o]*W_lin[q,o] + b_lin[q] ----
__global__ __launch_bounds__(256) void out_kernel(const float* __restrict__ x2,
                                                  const float* __restrict__ Wl,
                                                  const float* __restrict__ bl,
                                                  float* __restrict__ out,
                                                  const float* __restrict__ ss) {
    __shared__ float Wt[64][129];
    __shared__ float xl[64][64];
    const int tid = threadIdx.x;
    const int n0 = blockIdx.x * 64;
    for (int f = tid; f < 8192; f += 256) {
        int q = f >> 6, o = f & 63;
        Wt[o][q] = Wl[f];
    }
    for (int f = tid; f < 1024; f += 256) {
        int r = f >> 4, c = f & 15;
        f32x4 xv = *reinterpret_cast<const f32x4*>(x2 + (size_t)(n0 + r) * 64 + c * 4);
        const f32x4 sc = *reinterpret_cast<const f32x4*>(ss + c * 4);
        const f32x4 sh = *reinterpret_cast<const f32x4*>(ss + 64 + c * 4);
        xv = bn4(xv, sc, sh);
        *reinterpret_cast<f32x4*>(&xl[r][c * 4]) = xv;
    }
    __syncthreads();
    const int q = tid & 127, ng = tid >> 7;
    float acc[32] = {};
    for (int o4 = 0; o4 < 16; ++o4) {
        float w0 = Wt[4 * o4 + 0][q], w1 = Wt[4 * o4 + 1][q];
        float w2 = Wt[4 * o4 + 2][q], w3 = Wt[4 * o4 + 3][q];
#pragma unroll
        for (int k = 0; k < 32; ++k) {
            const f32x4 xv = *reinterpret_cast<const f32x4*>(&xl[ng + 2 * k][4 * o4]);
            acc[k] += xv.x * w0 + xv.y * w1 + xv.z * w2 + xv.w * w3;
        }
    }
    const float b = bl[q];
#pragma unroll
    for (int k = 0; k < 32; ++k)
        out[(size_t)(n0 + ng + 2 * k) * 128 + q] = acc[k] + b;
}

extern "C" void kernel_launch(void* const* d_in, const int* in_sizes, int n_in,
                              void* d_out, int out_size, void* d_ws, size_t ws_size,
                              hipStream_t stream) {
    const float* nf      = (const float*)d_in[0];
    const int*   ei      = (const int*)d_in[1];
    const float* ef      = (const float*)d_in[2];
    const float* W_edge0 = (const float*)d_in[4];
    const float* b_edge0 = (const float*)d_in[5];
    const float* W_root0 = (const float*)d_in[6];
    const float* b_root0 = (const float*)d_in[7];
    const float* gamma0  = (const float*)d_in[8];
    const float* beta0   = (const float*)d_in[9];
    const float* W_edge1 = (const float*)d_in[10];
    const float* b_edge1 = (const float*)d_in[11];
    const float* W_root1 = (const float*)d_in[12];
    const float* b_root1 = (const float*)d_in[13];
    const float* gamma1  = (const float*)d_in[14];
    const float* beta1   = (const float*)d_in[15];
    const float* W_lin   = (const float*)d_in[16];
    const float* b_lin   = (const float*)d_in[17];

    const int N = in_sizes[0] / 64;   // 8192
    const int E = in_sizes[1] / 2;    // 32768
    const int* src = ei;
    const int* dst = ei + E;

    unsigned short* ef_bs = (unsigned short*)d_ws;         // E*64 shorts (CSR)
    unsigned short* wbs0  = ef_bs + (size_t)E * 64;        // 262144
    unsigned short* wbs1  = wbs0 + 262144;                 // 262144
    float* msg   = (float*)(wbs1 + 262144);                // E*64 f32 (CSR)
    float* aggr0 = msg + (size_t)E * 64;                   // N*64
    float* aggr1 = aggr0 + (size_t)N * 64;                 // N*64
    float* NBbuf = aggr1 + (size_t)N * 64;                 // N*64
    float* stats = NBbuf + (size_t)N * 64;                 // 256
    float* ssbuf = stats + 256;                            // 256
    int*   cnt   = (int*)(ssbuf + 256);                    // 2
    int*   hist  = cnt + 2;                                // N
    int*   ofs   = hist + N;                               // N+1
    int*   cur   = ofs + N + 1;                            // N
    int*   perm  = cur + N;                                // E
    int*   src_s = perm + E;                               // E

    const float invN = 1.0f / (float)N;

    hipMemsetAsync(hist, 0, N * sizeof(int), stream);
    prep<<<(65536 + E) / 256, 256, 0, stream>>>(W_edge0, W_edge1, wbs0, wbs1,
                                                stats, cnt, dst, hist, E);
    scan_kernel<<<1, 256, 0, stream>>>(hist, ofs, cur, N);
    scatter_kernel<<<E / 256, 256, 0, stream>>>(dst, cur, perm);
    reorder_ef<<<E * 16 / 256, 256, 0, stream>>>(ef, perm, src, ef_bs, src_s);

    // ---- layer 0 ----
    node_mm2<<<dim3(N / 64, 2), 256, 0, stream>>>(nf, W_root0, b_root0, aggr0,
                                                  b_edge0, NBbuf, nullptr);
    msg_fused<<<E / 128, 512, 0, stream>>>(ef_bs, wbs0, nf, NBbuf, src_s, msg, nullptr);
    gather_k<<<N / 4, 256, 0, stream>>>(msg, ofs, aggr0);
    bn_stats<<<N / 128, 256, 0, stream>>>(aggr0, stats, gamma0, beta0, ssbuf,
                                          invN, cnt + 0, N / 128);

    // ---- layer 1 (x1 = BN(aggr0) applied on load everywhere) ----
    node_mm2<<<dim3(N / 64, 2), 256, 0, stream>>>(aggr0, W_root1, b_root1, aggr1,
                                                  b_edge1, NBbuf, ssbuf);
    msg_fused<<<E / 128, 512, 0, stream>>>(ef_bs, wbs1, aggr0, NBbuf, src_s, msg, ssbuf);
    gather_k<<<N / 4, 256, 0, stream>>>(msg, ofs, aggr1);
    bn_stats<<<N / 128, 256, 0, stream>>>(aggr1, stats + 128, gamma1, beta1, ssbuf + 128,
                                          invN, cnt + 1, N / 128);

    // ---- final linear (x2 = BN(aggr1) on load) ----
    out_kernel<<<N / 64, 256, 0, stream>>>(aggr1, W_lin, b_lin, (float*)d_out, ssbuf + 128);
}